// Round 1
// baseline (73.358 us; speedup 1.0000x reference)
//
#include <hip/hip_runtime.h>

#define GRIDDIM 512  // G in the reference (CP_locs is G x G x 2)

__global__ __launch_bounds__(256) void catmullrom_sqerr_kernel(
    const float2* __restrict__ ch1,      // (N) float2
    const float2* __restrict__ CP_locs,  // (G*G) float2
    const int2*  __restrict__ CP_idx,    // (N) int2
    const float2* __restrict__ r,        // (N) float2
    float* __restrict__ out,             // scalar
    int N)
{
    float acc = 0.0f;
    const int stride = gridDim.x * blockDim.x;
    for (int n = blockIdx.x * blockDim.x + threadIdx.x; n < N; n += stride) {
        float2 rv = r[n];
        float x = rv.x - floorf(rv.x);
        float y = rv.y - floorf(rv.y);

        // Catmull-Rom weights: W = [t^3,t^2,t,1] @ A
        float x2 = x * x, x3 = x2 * x;
        float wx[4];
        wx[0] = -0.5f * x3 + x2 - 0.5f * x;
        wx[1] =  1.5f * x3 - 2.5f * x2 + 1.0f;
        wx[2] = -1.5f * x3 + 2.0f * x2 + 0.5f * x;
        wx[3] =  0.5f * (x3 - x2);
        float y2 = y * y, y3 = y2 * y;
        float wy[4];
        wy[0] = -0.5f * y3 + y2 - 0.5f * y;
        wy[1] =  1.5f * y3 - 2.5f * y2 + 1.0f;
        wy[2] = -1.5f * y3 + 2.0f * y2 + 0.5f * y;
        wy[3] =  0.5f * (y3 - y2);

        int2 idx = CP_idx[n];
        const int ib = idx.x - 1;   // ii = idx.x + {-1,0,1,2}
        const int jb = idx.y - 1;

        float mx = 0.0f, my = 0.0f;
        #pragma unroll
        for (int i = 0; i < 4; ++i) {
            const float2* row = CP_locs + (size_t)(ib + i) * GRIDDIM + jb;
            float sx = 0.0f, sy = 0.0f;
            #pragma unroll
            for (int j = 0; j < 4; ++j) {
                float2 q = row[j];   // 4 consecutive float2 = 32 contiguous B
                sx = fmaf(wy[j], q.x, sx);
                sy = fmaf(wy[j], q.y, sy);
            }
            mx = fmaf(wx[i], sx, mx);
            my = fmaf(wx[i], sy, my);
        }

        float2 c = ch1[n];
        float dx = c.x - mx;
        float dy = c.y - my;
        acc = fmaf(dx, dx, acc);
        acc = fmaf(dy, dy, acc);
    }

    // wave (64-lane) reduction
    #pragma unroll
    for (int off = 32; off > 0; off >>= 1)
        acc += __shfl_down(acc, off, 64);

    __shared__ float wave_sums[4];  // 256 threads / 64 = 4 waves
    const int lane = threadIdx.x & 63;
    const int wid  = threadIdx.x >> 6;
    if (lane == 0) wave_sums[wid] = acc;
    __syncthreads();
    if (threadIdx.x == 0) {
        float s = wave_sums[0] + wave_sums[1] + wave_sums[2] + wave_sums[3];
        atomicAdd(out, s);
    }
}

extern "C" void kernel_launch(void* const* d_in, const int* in_sizes, int n_in,
                              void* d_out, int out_size, void* d_ws, size_t ws_size,
                              hipStream_t stream) {
    const float2* ch1     = (const float2*)d_in[0];
    const float2* CP_locs = (const float2*)d_in[1];
    const int2*   CP_idx  = (const int2*)d_in[2];
    const float2* r       = (const float2*)d_in[3];
    float* out = (float*)d_out;

    const int N = in_sizes[0] / 2;  // ch1 is (N,2) floats

    // Harness poisons d_out once and never re-poisons; zero it every call.
    hipMemsetAsync(out, 0, sizeof(float) * out_size, stream);

    int blocks = (N + 255) / 256;
    if (blocks > 2048) blocks = 2048;
    catmullrom_sqerr_kernel<<<blocks, 256, 0, stream>>>(ch1, CP_locs, CP_idx, r, out, N);
}